// Round 4
// baseline (234.806 us; speedup 1.0000x reference)
//
#include <hip/hip_runtime.h>
#include <math.h>

#define M_LEN 40000
#define B_SZ 16
#define K_TAPS 201
#define T_HALF 100
#define L_OUT 39800          // M_LEN - K_TAPS + 1
#define TL 512               // outputs per block
#define NTILES 78            // ceil(L_OUT / TL)
#define NP 712               // TL + K_TAPS - 1
#define NPS 714              // NP + 2 : staged series positions
#define NPX 716              // NP + 4 : x positions
#define XSTR 720             // x f16 stride
#define PAIRS 360            // staged series pairs
#define SSTR 362             // series pair-array stride in dwords (even)
#define NSER 20
#define WPP 104              // weight pairs per array (208 taps)
#define NWARR 28             // 4 base + 2 sg x 12
#define NTHR 512             // threads per block (2 outputs per thread)

typedef unsigned int uint;
typedef __fp16 h2 __attribute__((ext_vector_type(2)));

static __device__ __forceinline__ h2 U2H(uint u){ h2 r; __builtin_memcpy(&r,&u,4); return r; }
static __device__ __forceinline__ uint H2U(h2 h){ uint r; __builtin_memcpy(&r,&h,4); return r; }

#define FDOT2(w,v,acc) (acc) = __builtin_amdgcn_fdot2((w),(v),(acc),false)

// ---------------- prep kernel -------------------------------------------------
// Weight arrays (WPP uints each): 0 wx_v0, 1 wx_v1, 2 wc_v0, 3 wc_v1,
// then per sg block at 4+sg*12: kind pairs (v0,v1) for
// kind 0 wPr, 1 wPi, 2 wNr, 3 wNi, 4 wPsum(=wPr+wPi), 5 wNsum(=wNr+wNi)
// (Karatsuba conv: sum-weights replace the old negated copies.)
// version 0: pair p = (w[2p], w[2p+1]); version 1: (w[2p-1], w[2p])
static __device__ float wkind(int kind, int sg, int t,
                              const float* wr, const float* wi) {
    if (kind == 0) return (t >= 0 && t <= 200) ? wr[(2 + sg) * K_TAPS + t] : 0.f;
    if (kind == 1) return (t >= 0 && t <= 200) ? wi[(2 + sg) * K_TAPS + t] : 0.f;
    int tt = t - (sg + 1);
    if (kind == 2) return (tt >= 0 && tt <= 200) ? wr[(1 - sg) * K_TAPS + tt] : 0.f;
    if (kind == 3) return (tt >= 0 && tt <= 200) ? wi[(1 - sg) * K_TAPS + tt] : 0.f;
    if (kind == 4) return wkind(0, sg, t, wr, wi) + wkind(1, sg, t, wr, wi);
    return wkind(2, sg, t, wr, wi) + wkind(3, sg, t, wr, wi);
}

__global__ void prep_weights(const float* __restrict__ wx, const float* __restrict__ wc,
                             const float* __restrict__ wr, const float* __restrict__ wi,
                             uint* __restrict__ W) {
    int idx = blockIdx.x * 256 + threadIdx.x;
    if (idx >= NWARR * WPP) return;
    int p = idx % WPP;
    int a = idx / WPP;
    float f0, f1;
    if (a < 4) {
        int ver = a & 1;
        const float* src = (a < 2) ? wx : wc;
        int t0 = 2 * p - ver;
        f0 = (t0     >= 0 && t0     <= 200) ? src[t0]     : 0.f;
        f1 = (t0 + 1 >= 0 && t0 + 1 <= 200) ? src[t0 + 1] : 0.f;
    } else {
        int q = a - 4;
        int sg = q / 12, r = q % 12;
        int kind = r >> 1, ver = r & 1;
        int t0 = 2 * p - ver;
        f0 = wkind(kind, sg, t0,     wr, wi);
        f1 = wkind(kind, sg, t0 + 1, wr, wi);
    }
    W[idx] = H2U(__builtin_amdgcn_cvt_pkrtz(f0, f1));
}

// ---------------- window + dot helpers ----------------------------------------
// 2-output window: 8 packed pairs (16 taps). Scalar dword reads; base may be
// 4B-aligned only (odd g) -> compiler fuses into ds_read2_b32 (no align req).
struct Win8 { h2 hp[8]; };

static __device__ __forceinline__ Win8 readwin(const uint* base, int ko) {
    Win8 w;
#pragma unroll
    for (int j = 0; j < 8; ++j) w.hp[j] = U2H(base[ko + j]);
    return w;
}

static __device__ __forceinline__ Win8 winadd(const Win8& a, const Win8& b) {
    Win8 w;
#pragma unroll
    for (int j = 0; j < 8; ++j) w.hp[j] = a.hp[j] + b.hp[j];   // v_pk_add_f16
    return w;
}

static __device__ __forceinline__ Win8 winsub(const Win8& a, const Win8& b) {
    Win8 w;
#pragma unroll
    for (int j = 0; j < 8; ++j) w.hp[j] = a.hp[j] - b.hp[j];   // v_pk_add_f16 neg
    return w;
}

// 1 weight vector (2 versions) -> 2 f32 accs (even/odd output). 16 fdot2.
static __device__ __forceinline__ void dot1(const Win8& W, const uint* __restrict__ W0,
                                            int ko, float* acc) {
    const uint* W1 = W0 + WPP;
#pragma unroll
    for (int P = 0; P < 8; ++P) {
        FDOT2(U2H(W0[ko + P]), W.hp[P], acc[0]);
        FDOT2(U2H(W1[ko + P]), W.hp[P], acc[1]);
    }
}

// 2 weight vectors -> 2 f32 acc pairs. 32 fdot2.
static __device__ __forceinline__ void dot2w(const Win8& W,
                                             const uint* __restrict__ WA,
                                             const uint* __restrict__ WB,
                                             int ko, float* accA, float* accB) {
    const uint* WA1 = WA + WPP; const uint* WB1 = WB + WPP;
#pragma unroll
    for (int P = 0; P < 8; ++P) {
        FDOT2(U2H(WA[ko + P]),  W.hp[P], accA[0]);
        FDOT2(U2H(WA1[ko + P]), W.hp[P], accA[1]);
        FDOT2(U2H(WB[ko + P]),  W.hp[P], accB[0]);
        FDOT2(U2H(WB1[ko + P]), W.hp[P], accB[1]);
    }
}

static __device__ __forceinline__ void calc_series(
        const _Float16 (*sxr)[XSTR], const _Float16 (*sxi)[XSTR], int pos, float* v) {
    const int ix = pos + 2;
    float x0r = (float)sxr[0][ix], x0i = (float)sxi[0][ix];
    float x1r = (float)sxr[1][ix], x1i = (float)sxi[1][ix];
    float p0 = x0r * x0r + x0i * x0i;
    float p1 = x1r * x1r + x1i * x1i;
    v[0] = 2.f * p0 + p1;
    v[1] = 2.f * p1 + p0;
    v[2] = x0r * x1r + x0i * x1i;       // qr
    v[3] = x0i * x1r - x0r * x1i;       // qi
#pragma unroll
    for (int sg = 0; sg < 2; ++sg) {
        const int jx = ix - (sg + 1);
        float a0r = (float)sxr[0][jx], a0i = (float)sxi[0][jx];
        float a1r = (float)sxr[1][jx], a1i = (float)sxi[1][jx];
        float U0r = x0r * a0r + x0i * a0i;
        float U0i = x0i * a0r - x0r * a0i;
        float U1r = x1r * a1r + x1i * a1i;
        float U1i = x1i * a1r - x1r * a1i;
        const int ba = 4 + sg * 8;
        v[ba + 0] = 2.f * U0r + U1r;
        v[ba + 1] = 2.f * U1r + U0r;
        v[ba + 2] = 2.f * U0i + U1i;
        v[ba + 3] = 2.f * U1i + U0i;
        v[ba + 4] = x0r * a1r + x0i * a1i;  // Br0
        v[ba + 5] = x1r * a0r + x1i * a0i;  // Br1
        v[ba + 6] = x0i * a1r - x0r * a1i;  // Bi0
        v[ba + 7] = x1i * a0r - x1r * a0i;  // Bi1
    }
}

// 512 threads, 2 outputs/thread. Karatsuba complex conv: each of the 8 complex
// FWM convs = 3 real convs (was 4): 35 -> 27 real convs per (pos,nn) unit.
// Sum/diff windows derived in registers (pk_add_f16) so LDS traffic is
// unchanged vs R3 (conflict-free). fdot2/thread: 7280 -> 5616 (+832 pk ops).
__global__ __launch_bounds__(NTHR, 4) void snse_kernel(
    const float* __restrict__ g_xr, const float* __restrict__ g_xi,
    const float* __restrict__ g_ti, const float* __restrict__ g_c00,
    const float* __restrict__ g_wx, const float* __restrict__ g_wc,
    const uint* __restrict__ Wg,
    float* __restrict__ g_out)
{
    __shared__ __align__(16) uint SE[NSER * SSTR];              // 28960 B
    __shared__ _Float16 s_xr_h[2][XSTR], s_xi_h[2][XSTR];       //  5760 B

    const int tid = threadIdx.x;
    const int b   = blockIdx.y;
    const int l0  = blockIdx.x * TL;

    const float tdb    = g_ti[b * 4 + 0];
    const float P      = expf(tdb * 0.23025850929940457f) * 0.5f;
    const float sP     = sqrtf(P);
    const float inv_sP = 1.0f / sP;
    const float C00    = g_c00[0];

    for (int idx = tid; idx < 2 * NPX; idx += NTHR) {
        int pidx = idx >> 1, ch = idx & 1;
        int m = l0 - 2 + pidx;
        int mw = m < 0 ? m + M_LEN : (m >= M_LEN ? m - M_LEN : m);
        int gg = (b * M_LEN + mw) * 2 + ch;
        s_xr_h[ch][pidx] = (_Float16)(g_xr[gg] * sP);
        s_xi_h[ch][pidx] = (_Float16)(g_xi[gg] * sP);
    }
    __syncthreads();

    // stage packed f16 series pairs; zero-fill beyond NPS (NaN guard)
    for (int p = tid; p < PAIRS; p += NTHR) {
        float v0[NSER], v1[NSER];
#pragma unroll
        for (int a = 0; a < NSER; ++a) { v0[a] = 0.f; v1[a] = 0.f; }
        const int m0 = 2 * p, m1 = 2 * p + 1;
        if (m0 < NPS) calc_series(s_xr_h, s_xi_h, m0, v0);
        if (m1 < NPS) calc_series(s_xr_h, s_xi_h, m1, v1);
#pragma unroll
        for (int a = 0; a < NSER; ++a)
            SE[a * SSTR + p] = H2U(__builtin_amdgcn_cvt_pkrtz(v0[a], v1[a]));
    }
    __syncthreads();

    const int g  = tid & 255;       // 256 output-pair groups
    const int nn = tid >> 8;        // channel (wave-uniform: flips at 256)
    const int pb = g;               // series pair base for output 2g

    float acc_ix[2] = {}, acc_qr[2] = {}, acc_qi[2] = {};
    // Karatsuba partial accumulators, [sg][o]
    float aP1[2][2] = {}, aP2[2][2] = {}, aP3[2][2] = {};
    float aN1[2][2] = {}, aN2[2][2] = {}, aN3[2][2] = {};
    float bP1[2][2] = {}, bP2[2][2] = {}, bP3[2][2] = {};
    float bN1[2][2] = {}, bN2[2][2] = {}, bN3[2][2] = {};

    const uint* bps = &SE[nn * SSTR + pb];
    const uint* bqr = &SE[2 * SSTR + pb];
    const uint* bqi = &SE[3 * SSTR + pb];
    const uint *bAr[2], *bAi[2], *bBor[2], *bBoi[2], *bBxr[2], *bBxi[2];
#pragma unroll
    for (int sg = 0; sg < 2; ++sg) {
        const int ba = 4 + sg * 8;
        bAr[sg]  = &SE[(ba + 0 + nn) * SSTR + pb];
        bAi[sg]  = &SE[(ba + 2 + nn) * SSTR + pb];
        bBor[sg] = &SE[(ba + 4 + nn) * SSTR + pb];
        bBoi[sg] = &SE[(ba + 6 + nn) * SSTR + pb];
        bBxr[sg] = &SE[(ba + 4 + (1 - nn)) * SSTR + pb];
        bBxi[sg] = &SE[(ba + 6 + (1 - nn)) * SSTR + pb];
    }

    // monolithic k-loop; sg unrolled (runtime acc indices -> scratch)
#pragma unroll 1
    for (int k = 0; k < 13; ++k) {
        const int ko = 8 * k;
        { Win8 w = readwin(bps, ko); dot1(w, Wg + 0 * WPP, ko, acc_ix); }
        { Win8 w = readwin(bqr, ko); dot1(w, Wg + 2 * WPP, ko, acc_qr); }
        { Win8 w = readwin(bqi, ko); dot1(w, Wg + 2 * WPP, ko, acc_qi); }
#pragma unroll
        for (int sg = 0; sg < 2; ++sg) {
            const uint* G = Wg + (4 + sg * 12) * WPP;
            // G offsets: +0 wPr, +2 wPi, +4 wNr, +6 wNi, +8 wPsum, +10 wNsum
            {
                Win8 wAr = readwin(bAr[sg], ko);
                Win8 wAi = readwin(bAi[sg], ko);
                dot2w(wAr, G + 0 * WPP, G + 4 * WPP, ko, aP1[sg], aN1[sg]);
                dot2w(wAi, G + 2 * WPP, G + 6 * WPP, ko, aP2[sg], aN2[sg]);
                Win8 wS = winadd(wAr, wAi);
                dot1(wS, G + 8 * WPP, ko, aP3[sg]);
                Win8 wD = winsub(wAr, wAi);
                dot1(wD, G + 10 * WPP, ko, aN3[sg]);
            }
            {
                Win8 wBor = readwin(bBor[sg], ko);
                Win8 wBoi = readwin(bBoi[sg], ko);
                dot1(wBor, G + 0 * WPP, ko, bP1[sg]);
                dot1(wBoi, G + 2 * WPP, ko, bP2[sg]);
                Win8 wBs = winadd(wBor, wBoi);
                dot1(wBs, G + 8 * WPP, ko, bP3[sg]);
                Win8 wBxr = readwin(bBxr[sg], ko);
                Win8 wBxi = readwin(bBxi[sg], ko);
                dot1(wBxr, G + 4 * WPP, ko, bN1[sg]);
                dot1(wBxi, G + 6 * WPP, ko, bN2[sg]);
                Win8 wBd = winsub(wBxr, wBxi);
                dot1(wBd, G + 10 * WPP, ko, bN3[sg]);
            }
        }
    }

    // Karatsuba recombination -> fAr/fAi/fBr/fBi[si][o]
    // si mapping: sip = 2+sg, sin = 1-sg (shifts ssf = {-2,-1,1,2})
    float fAr[4][2], fAi[4][2], fBr[4][2], fBi[4][2];
#pragma unroll
    for (int sg = 0; sg < 2; ++sg) {
        const int sip = 2 + sg, sin_ = 1 - sg;
#pragma unroll
        for (int o = 0; o < 2; ++o) {
            fAr[sip][o]  = aP1[sg][o] - aP2[sg][o];
            fAi[sip][o]  = aP3[sg][o] - aP1[sg][o] - aP2[sg][o];
            fAr[sin_][o] = aN1[sg][o] + aN2[sg][o];
            fAi[sin_][o] = aN3[sg][o] - aN1[sg][o] + aN2[sg][o];
            fBr[sip][o]  = bP1[sg][o] - bP2[sg][o];
            fBi[sip][o]  = bP3[sg][o] - bP1[sg][o] - bP2[sg][o];
            fBr[sin_][o] = bN1[sg][o] + bN2[sg][o];
            fBi[sin_][o] = bN3[sg][o] - bN1[sg][o] + bN2[sg][o];
        }
    }

    // zero-center-tap correction (zcv only); f16-rounded weights to match conv
    {
        const float wx100 = (float)(_Float16)g_wx[T_HALF];
        const float wc100 = (float)(_Float16)g_wc[T_HALF];
#pragma unroll
        for (int o = 0; o < 2; ++o) {
            const int pos = 2 * g + o + T_HALF;
            const int pp = pos >> 1, pe = pos & 1;
            h2 vps = U2H(SE[nn * SSTR + pp]);
            h2 vqr = U2H(SE[2 * SSTR + pp]);
            h2 vqi = U2H(SE[3 * SSTR + pp]);
            acc_ix[o] = fmaf(-wx100, (float)vps[pe], acc_ix[o]);
            acc_qr[o] = fmaf(-wc100, (float)vqr[pe], acc_qr[o]);
            acc_qi[o] = fmaf(-wc100, (float)vqi[pe], acc_qi[o]);
        }
    }

    // epilogue
    const int ssf[4] = {-2, -1, 1, 2};
#pragma unroll
    for (int o = 0; o < 2; ++o) {
        const int lrel = 2 * g + o;
        const int l = l0 + lrel;
        const int xc = lrel + T_HALF + 2;
        float X0r = (float)s_xr_h[0][xc], X0i = (float)s_xi_h[0][xc];
        float X1r = (float)s_xr_h[1][xc], X1i = (float)s_xi_h[1][xc];
        float pw  = X0r * X0r + X0i * X0i + X1r * X1r + X1i * X1i;
        float phi = C00 * pw + 2.f * acc_ix[o];
        float sph, cph;
        __sincosf(phi, &sph, &cph);
        float qcr = acc_qr[o];
        float qci = nn ? -acc_qi[o] : acc_qi[o];
        float br_ = nn ? X1r : X0r, bi_ = nn ? X1i : X0i;
        float or_ = nn ? X0r : X1r, oi_ = nn ? X0i : X1i;
        float ici_r = -(or_ * qci + oi_ * qcr);
        float ici_i =   or_ * qcr - oi_ * qci;
        float fw_r = 0.f, fw_i = 0.f;
#pragma unroll
        for (int si = 0; si < 4; ++si) {
            int sx = xc - ssf[si];
            float xnr  = (float)s_xr_h[nn][sx],     xni = (float)s_xi_h[nn][sx];
            float xor_ = (float)s_xr_h[1 - nn][sx], xoi = (float)s_xi_h[1 - nn][sx];
            fw_r += xnr * fAr[si][o] - xni * fAi[si][o]
                  + xor_ * fBr[si][o] - xoi * fBi[si][o];
            fw_i += xnr * fAi[si][o] + xni * fAr[si][o]
                  + xor_ * fBi[si][o] + xoi * fBr[si][o];
        }
        float out_r = br_ * cph - bi_ * sph + ici_r + fw_r;
        float out_i = br_ * sph + bi_ * cph + ici_i + fw_i;
        if (l < L_OUT) {
            int oidx = (((b * L_OUT) + l) * 2 + nn) * 2;
            g_out[oidx]     = out_r * inv_sP;
            g_out[oidx + 1] = out_i * inv_sP;
        }
    }
}

extern "C" void kernel_launch(void* const* d_in, const int* in_sizes, int n_in,
                              void* d_out, int out_size, void* d_ws, size_t ws_size,
                              hipStream_t stream) {
    const float* xr  = (const float*)d_in[0];
    const float* xi  = (const float*)d_in[1];
    const float* ti  = (const float*)d_in[2];
    const float* c00 = (const float*)d_in[3];
    const float* wx  = (const float*)d_in[4];
    const float* wc  = (const float*)d_in[5];
    const float* wr  = (const float*)d_in[6];
    const float* wi  = (const float*)d_in[7];
    float* out = (float*)d_out;
    uint* W = (uint*)d_ws;   // NWARR*WPP*4 = 11648 bytes

    prep_weights<<<dim3((NWARR * WPP + 255) / 256), dim3(256), 0, stream>>>(wx, wc, wr, wi, W);

    dim3 grid(NTILES, B_SZ, 1);
    dim3 block(NTHR, 1, 1);
    snse_kernel<<<grid, block, 0, stream>>>(xr, xi, ti, c00, wx, wc, W, out);
}

// Round 5
// 190.556 us; speedup vs baseline: 1.2322x; 1.2322x over previous
//
#include <hip/hip_runtime.h>
#include <math.h>

#define M_LEN 40000
#define B_SZ 16
#define K_TAPS 201
#define T_HALF 100
#define L_OUT 39800
#define TL 256               // outputs per block
#define NTILES 156           // ceil(L_OUT / TL)
#define NP 456               // TL + K_TAPS - 1
#define NPS 458              // NP + 2 (guard)
#define NPX 460              // x positions staged
#define XSTR 464             // x f16 stride
#define SSTR 244             // series row stride in dwords (488 f16 elems)
#define NSER 20
#define KT 14                // k-tiles: 14*16 = 224 >= 201 taps (rest zero-wt)
#define CSTR 258             // Cbuf position stride (f16)
#define NSLOT 68
#define NTHR 512

typedef unsigned int uint;
typedef unsigned short ushort_;
typedef __fp16 h4 __attribute__((ext_vector_type(4)));
typedef float f4 __attribute__((ext_vector_type(4)));

static __device__ __forceinline__ float half_of(uint u, int hi) {
    ushort_ us = hi ? (ushort_)(u >> 16) : (ushort_)(u & 0xffffu);
    _Float16 h; __builtin_memcpy(&h, &us, 2); return (float)h;
}
static __device__ __forceinline__ h4 mk4(uint a, uint b) {
    uint uu[2] = {a, b}; h4 h; __builtin_memcpy(&h, uu, 8); return h;
}

// ---------------- prep kernel: B weight panel [16 cols][224 taps] f16 --------
// col 0: wx; col 1: wc; cols 2+4sg+{0,1,2,3}: wPr,wPi,wNr,wNi for sg; 10-15: 0
__global__ void prep_weights(const float* __restrict__ wx, const float* __restrict__ wc,
                             const float* __restrict__ wr, const float* __restrict__ wi,
                             _Float16* __restrict__ Wb) {
    int idx = blockIdx.x * 256 + threadIdx.x;
    if (idx >= 16 * 224) return;
    int n = idx / 224, t = idx % 224;
    float f = 0.f;
    if (n == 0)      f = (t <= 200) ? wx[t] : 0.f;
    else if (n == 1) f = (t <= 200) ? wc[t] : 0.f;
    else if (n < 10) {
        int q = n - 2, sg = q >> 2, c = q & 3;
        if (c < 2) {                       // wPr / wPi
            f = (t <= 200) ? ((c == 1) ? wi : wr)[(2 + sg) * K_TAPS + t] : 0.f;
        } else {                           // wNr / wNi (shifted taps)
            int tt = t - (sg + 1);
            f = (tt >= 0 && tt <= 200) ? ((c == 3) ? wi : wr)[(1 - sg) * K_TAPS + tt] : 0.f;
        }
    }
    Wb[idx] = (_Float16)f;
}

// ---------------- series construction (identical math to verified R0-R4) -----
static __device__ __forceinline__ void calc_series(
        const _Float16 (*sxr)[XSTR], const _Float16 (*sxi)[XSTR], int pos, float* v) {
    const int ix = pos + 2;
    float x0r = (float)sxr[0][ix], x0i = (float)sxi[0][ix];
    float x1r = (float)sxr[1][ix], x1i = (float)sxi[1][ix];
    float p0 = x0r * x0r + x0i * x0i;
    float p1 = x1r * x1r + x1i * x1i;
    v[0] = 2.f * p0 + p1;
    v[1] = 2.f * p1 + p0;
    v[2] = x0r * x1r + x0i * x1i;       // qr
    v[3] = x0i * x1r - x0r * x1i;       // qi
#pragma unroll
    for (int sg = 0; sg < 2; ++sg) {
        const int jx = ix - (sg + 1);
        float a0r = (float)sxr[0][jx], a0i = (float)sxi[0][jx];
        float a1r = (float)sxr[1][jx], a1i = (float)sxi[1][jx];
        float U0r = x0r * a0r + x0i * a0i;
        float U0i = x0i * a0r - x0r * a0i;
        float U1r = x1r * a1r + x1i * a1i;
        float U1i = x1i * a1r - x1r * a1i;
        const int ba = 4 + sg * 8;
        v[ba + 0] = 2.f * U0r + U1r;        // A0r
        v[ba + 1] = 2.f * U1r + U0r;        // A1r
        v[ba + 2] = 2.f * U0i + U1i;        // A0i
        v[ba + 3] = 2.f * U1i + U0i;        // A1i
        v[ba + 4] = x0r * a1r + x0i * a1i;  // Br0
        v[ba + 5] = x1r * a0r + x1i * a0i;  // Br1
        v[ba + 6] = x0i * a1r - x0r * a1i;  // Bi0
        v[ba + 7] = x1i * a0r - x1r * a0i;  // Bi1
    }
}

// MFMA conv kernel: VALU walls out at ~118us for 9.3e9 MACs (5 rounds pinned
// at 176-187us, MfmaUtil=0); matrix pipe does all convs here instead.
__global__ __launch_bounds__(NTHR, 4) void snse_kernel(
    const float* __restrict__ g_xr, const float* __restrict__ g_xi,
    const float* __restrict__ g_ti, const float* __restrict__ g_c00,
    const float* __restrict__ g_wx, const float* __restrict__ g_wc,
    const _Float16* __restrict__ Wb,
    float* __restrict__ g_out)
{
    __shared__ uint SEe[NSER * SSTR];                       // 19520 B
    __shared__ uint SEo[NSER * SSTR];                       // 19520 B (shift-1)
    __shared__ _Float16 CB[NSLOT * CSTR];                   // 35088 B
    __shared__ _Float16 s_xr_h[2][XSTR], s_xi_h[2][XSTR];   //  3712 B

    const int tid = threadIdx.x;
    const int b   = blockIdx.y;
    const int l0  = blockIdx.x * TL;

    const float tdb    = g_ti[b * 4 + 0];
    const float P      = expf(tdb * 0.23025850929940457f) * 0.5f;
    const float sP     = sqrtf(P);
    const float inv_sP = 1.0f / sP;
    const float C00    = g_c00[0];

    // ---- stage x (f16, scaled) ----
    for (int idx = tid; idx < 2 * NPX; idx += NTHR) {
        int pidx = idx >> 1, ch = idx & 1;
        int m = l0 - 2 + pidx;
        int mw = m < 0 ? m + M_LEN : (m >= M_LEN ? m - M_LEN : m);
        int gg = (b * M_LEN + mw) * 2 + ch;
        s_xr_h[ch][pidx] = (_Float16)(g_xr[gg] * sP);
        s_xi_h[ch][pidx] = (_Float16)(g_xi[gg] * sP);
    }
    __syncthreads();

    // ---- stage series (packed f16 pairs), zero beyond NPS ----
    for (int p = tid; p < SSTR; p += NTHR) {
        float v0[NSER], v1[NSER];
#pragma unroll
        for (int a = 0; a < NSER; ++a) { v0[a] = 0.f; v1[a] = 0.f; }
        const int m0 = 2 * p, m1 = 2 * p + 1;
        if (m0 < NPS) calc_series(s_xr_h, s_xi_h, m0, v0);
        if (m1 < NPS) calc_series(s_xr_h, s_xi_h, m1, v1);
#pragma unroll
        for (int a = 0; a < NSER; ++a) {
            uint u; h4 dummy; (void)dummy;
            _Float16 h0 = (_Float16)v0[a], h1 = (_Float16)v1[a];
            ushort_ s0, s1; __builtin_memcpy(&s0, &h0, 2); __builtin_memcpy(&s1, &h1, 2);
            u = (uint)s0 | ((uint)s1 << 16);
            SEe[a * SSTR + p] = u;
        }
    }
    __syncthreads();

    // ---- shifted copy: SEo[d] = elements (2d+1, 2d+2) ----
    for (int d = tid; d < NSER * SSTR; d += NTHR) {
        int row = d / SSTR, cc = d - row * SSTR;
        uint lo = SEe[d] >> 16;
        uint hi = (cc < SSTR - 1) ? (SEe[d + 1] << 16) : 0u;
        SEo[d] = lo | hi;
    }
    __syncthreads();

    // ---- MFMA conv phase ----
    // wave w: rho = parity, hs = position half, sgrp = series group (10 each)
    // chunks c=0..3: 16 stride-2 positions starting pbase0+32c
    {
        const int w    = tid >> 6;
        const int lane = tid & 63;
        const int cn   = lane & 15;   // A row m / B-C col
        const int gq   = lane >> 4;   // k-group / C row-quad
        const int rho  = w & 1, hs = (w >> 1) & 1, sgrp = w >> 2;
        const int pbase0 = hs * 128 + rho;

        h4 Bf[KT];
#pragma unroll
        for (int i = 0; i < KT; ++i) {
            h4 t; __builtin_memcpy(&t, Wb + cn * 224 + 16 * i + 4 * gq, 8);
            Bf[i] = t;
        }

        const uint* SEp = rho ? SEo : SEe;
        const int dw0 = ((pbase0 - rho) >> 1) + cn + 2 * gq;

#pragma unroll 1
        for (int as = 0; as < 10; ++as) {
            const int a = sgrp * 10 + as;
            const uint* Pa = SEp + a * SSTR + dw0;

            h4 F[KT];
#pragma unroll
            for (int i = 0; i < KT; ++i)
                F[i] = mk4(Pa[8 * i], Pa[8 * i + 1]);

            // slot for this lane's column (or -1)
            int slot = -1;
            if (a < 4) {
                if (cn == (a >> 1)) slot = a;
            } else {
                int cb = 2 + 4 * ((a - 4) >> 3);
                int ci = cn - cb;
                if (ci >= 0 && ci < 4) slot = 4 + (a - 4) * 4 + ci;
            }

#pragma unroll
            for (int c = 0; c < 4; ++c) {
                f4 Cc = {0.f, 0.f, 0.f, 0.f};
#pragma unroll
                for (int kt = 0; kt < KT; ++kt)
                    Cc = __builtin_amdgcn_mfma_f32_16x16x16f16(
                        F[(2 * c + kt) % KT], Bf[kt], Cc, 0, 0, 0);
                if (c < 3) {   // prefetch next chunk's 2 new frags
                    F[(2 * c) % KT]     = mk4(Pa[8 * (KT + 2 * c)],     Pa[8 * (KT + 2 * c) + 1]);
                    F[(2 * c + 1) % KT] = mk4(Pa[8 * (KT + 2 * c + 1)], Pa[8 * (KT + 2 * c + 1) + 1]);
                }
                if (slot >= 0) {
                    const int pb = pbase0 + 32 * c;
#pragma unroll
                    for (int r = 0; r < 4; ++r)
                        CB[slot * CSTR + pb + 2 * (4 * gq + r)] = (_Float16)Cc[r];
                }
            }
        }
    }
    __syncthreads();

    // ---- epilogue: one (pos, nn) unit per thread ----
    {
        const int pos = tid >> 1, nn = tid & 1;
        const int l = l0 + pos;

        const float wx100 = (float)(_Float16)g_wx[T_HALF];
        const float wc100 = (float)(_Float16)g_wc[T_HALF];

        float acc_ix = (float)CB[nn * CSTR + pos];
        float acc_qr = (float)CB[2 * CSTR + pos];
        float acc_qi = (float)CB[3 * CSTR + pos];

        const int pc = pos + T_HALF;
        acc_ix = fmaf(-wx100, half_of(SEe[nn * SSTR + (pc >> 1)], pc & 1), acc_ix);
        acc_qr = fmaf(-wc100, half_of(SEe[2 * SSTR + (pc >> 1)], pc & 1), acc_qr);
        acc_qi = fmaf(-wc100, half_of(SEe[3 * SSTR + (pc >> 1)], pc & 1), acc_qi);

        float fAr[4], fAi[4], fBr[4], fBi[4];
#pragma unroll
        for (int sg = 0; sg < 2; ++sg) {
            const int sip = 2 + sg, sin_ = 1 - sg;
            const int sb = 4 + 32 * sg;
            // S(si,ci) = CB[(sb + 4*si + ci)][pos]
#define SRD(si, ci) ((float)CB[(sb + 4 * (si) + (ci)) * CSTR + pos])
            fAr[sip]  = SRD(nn, 0)     - SRD(2 + nn, 1);
            fAi[sip]  = SRD(nn, 1)     + SRD(2 + nn, 0);
            fAr[sin_] = SRD(nn, 2)     + SRD(2 + nn, 3);
            fAi[sin_] = SRD(nn, 3)     - SRD(2 + nn, 2);
            fBr[sip]  = SRD(4 + nn, 0) - SRD(6 + nn, 1);
            fBi[sip]  = SRD(4 + nn, 1) + SRD(6 + nn, 0);
            fBr[sin_] = SRD(5 - nn, 2) + SRD(7 - nn, 3);
            fBi[sin_] = SRD(5 - nn, 3) - SRD(7 - nn, 2);
#undef SRD
        }

        const int xc = pos + T_HALF + 2;
        float X0r = (float)s_xr_h[0][xc], X0i = (float)s_xi_h[0][xc];
        float X1r = (float)s_xr_h[1][xc], X1i = (float)s_xi_h[1][xc];
        float pw  = X0r * X0r + X0i * X0i + X1r * X1r + X1i * X1i;
        float phi = C00 * pw + 2.f * acc_ix;
        float sph, cph;
        __sincosf(phi, &sph, &cph);
        float qcr = acc_qr;
        float qci = nn ? -acc_qi : acc_qi;
        float br_ = nn ? X1r : X0r, bi_ = nn ? X1i : X0i;
        float or_ = nn ? X0r : X1r, oi_ = nn ? X0i : X1i;
        float ici_r = -(or_ * qci + oi_ * qcr);
        float ici_i =   or_ * qcr - oi_ * qci;
        float fw_r = 0.f, fw_i = 0.f;
        const int ssf[4] = {-2, -1, 1, 2};
#pragma unroll
        for (int si = 0; si < 4; ++si) {
            int sx = xc - ssf[si];
            float xnr  = (float)s_xr_h[nn][sx],     xni = (float)s_xi_h[nn][sx];
            float xor_ = (float)s_xr_h[1 - nn][sx], xoi = (float)s_xi_h[1 - nn][sx];
            fw_r += xnr * fAr[si] - xni * fAi[si]
                  + xor_ * fBr[si] - xoi * fBi[si];
            fw_i += xnr * fAi[si] + xni * fAr[si]
                  + xor_ * fBi[si] + xoi * fBr[si];
        }
        float out_r = br_ * cph - bi_ * sph + ici_r + fw_r;
        float out_i = br_ * sph + bi_ * cph + ici_i + fw_i;
        if (l < L_OUT) {
            int oidx = (((b * L_OUT) + l) * 2 + nn) * 2;
            g_out[oidx]     = out_r * inv_sP;
            g_out[oidx + 1] = out_i * inv_sP;
        }
    }
}

extern "C" void kernel_launch(void* const* d_in, const int* in_sizes, int n_in,
                              void* d_out, int out_size, void* d_ws, size_t ws_size,
                              hipStream_t stream) {
    const float* xr  = (const float*)d_in[0];
    const float* xi  = (const float*)d_in[1];
    const float* ti  = (const float*)d_in[2];
    const float* c00 = (const float*)d_in[3];
    const float* wx  = (const float*)d_in[4];
    const float* wc  = (const float*)d_in[5];
    const float* wr  = (const float*)d_in[6];
    const float* wi  = (const float*)d_in[7];
    float* out = (float*)d_out;
    _Float16* Wb = (_Float16*)d_ws;   // 16*224*2 = 7168 bytes

    prep_weights<<<dim3((16 * 224 + 255) / 256), dim3(256), 0, stream>>>(wx, wc, wr, wi, Wb);

    dim3 grid(NTILES, B_SZ, 1);
    dim3 block(NTHR, 1, 1);
    snse_kernel<<<grid, block, 0, stream>>>(xr, xi, ti, c00, wx, wc, Wb, out);
}

// Round 6
// 170.755 us; speedup vs baseline: 1.3751x; 1.1160x over previous
//
#include <hip/hip_runtime.h>
#include <math.h>

#define M_LEN 40000
#define B_SZ 16
#define K_TAPS 201
#define T_HALF 100
#define L_OUT 39800
#define TL 256               // outputs per block
#define NTILES 156           // ceil(L_OUT / TL)
#define NP 456               // TL + K_TAPS - 1
#define NPS 458              // NP + 2 (guard)
#define NPX 460              // x positions staged
#define XSTR 464             // x f16 stride
#define SSTR 244             // series row stride in dwords (488 f16 elems)
#define NSER 20
#define KT 7                 // k-tiles: 7*32 = 224 >= 201 taps (rest zero-wt)
#define CSTR 258             // Cbuf position stride (f16)
#define NSLOT 68
#define NTHR 512

typedef unsigned int uint;
typedef unsigned short ushort_;
typedef __fp16 h8 __attribute__((ext_vector_type(8)));
typedef float f4 __attribute__((ext_vector_type(4)));

static __device__ __forceinline__ float half_of(uint u, int hi) {
    ushort_ us = hi ? (ushort_)(u >> 16) : (ushort_)(u & 0xffffu);
    _Float16 h; __builtin_memcpy(&h, &us, 2); return (float)h;
}
static __device__ __forceinline__ h8 mk8(uint a, uint b, uint c, uint d) {
    uint uu[4] = {a, b, c, d}; h8 h; __builtin_memcpy(&h, uu, 16); return h;
}

// ---------------- prep kernel: B weight panel [16 cols][224 taps] f16 --------
// col 0: wx; col 1: wc; cols 2+4sg+{0,1,2,3}: wPr,wPi,wNr,wNi for sg; 10-15: 0
__global__ void prep_weights(const float* __restrict__ wx, const float* __restrict__ wc,
                             const float* __restrict__ wr, const float* __restrict__ wi,
                             _Float16* __restrict__ Wb) {
    int idx = blockIdx.x * 256 + threadIdx.x;
    if (idx >= 16 * 224) return;
    int n = idx / 224, t = idx % 224;
    float f = 0.f;
    if (n == 0)      f = (t <= 200) ? wx[t] : 0.f;
    else if (n == 1) f = (t <= 200) ? wc[t] : 0.f;
    else if (n < 10) {
        int q = n - 2, sg = q >> 2, c = q & 3;
        if (c < 2) {                       // wPr / wPi
            f = (t <= 200) ? ((c == 1) ? wi : wr)[(2 + sg) * K_TAPS + t] : 0.f;
        } else {                           // wNr / wNi (shifted taps)
            int tt = t - (sg + 1);
            f = (tt >= 0 && tt <= 200) ? ((c == 3) ? wi : wr)[(1 - sg) * K_TAPS + tt] : 0.f;
        }
    }
    Wb[idx] = (_Float16)f;
}

// ---------------- series construction (identical math to verified R0-R5) -----
static __device__ __forceinline__ void calc_series(
        const _Float16 (*sxr)[XSTR], const _Float16 (*sxi)[XSTR], int pos, float* v) {
    const int ix = pos + 2;
    float x0r = (float)sxr[0][ix], x0i = (float)sxi[0][ix];
    float x1r = (float)sxr[1][ix], x1i = (float)sxi[1][ix];
    float p0 = x0r * x0r + x0i * x0i;
    float p1 = x1r * x1r + x1i * x1i;
    v[0] = 2.f * p0 + p1;
    v[1] = 2.f * p1 + p0;
    v[2] = x0r * x1r + x0i * x1i;       // qr
    v[3] = x0i * x1r - x0r * x1i;       // qi
#pragma unroll
    for (int sg = 0; sg < 2; ++sg) {
        const int jx = ix - (sg + 1);
        float a0r = (float)sxr[0][jx], a0i = (float)sxi[0][jx];
        float a1r = (float)sxr[1][jx], a1i = (float)sxi[1][jx];
        float U0r = x0r * a0r + x0i * a0i;
        float U0i = x0i * a0r - x0r * a0i;
        float U1r = x1r * a1r + x1i * a1i;
        float U1i = x1i * a1r - x1r * a1i;
        const int ba = 4 + sg * 8;
        v[ba + 0] = 2.f * U0r + U1r;        // A0r
        v[ba + 1] = 2.f * U1r + U0r;        // A1r
        v[ba + 2] = 2.f * U0i + U1i;        // A0i
        v[ba + 3] = 2.f * U1i + U0i;        // A1i
        v[ba + 4] = x0r * a1r + x0i * a1i;  // Br0
        v[ba + 5] = x1r * a0r + x1i * a0i;  // Br1
        v[ba + 6] = x0i * a1r - x0r * a1i;  // Bi0
        v[ba + 7] = x1i * a0r - x1r * a0i;  // Bi1
    }
}

// MFMA conv kernel, gfx950 doubled-K shape. R5 measured 16x16x16f16 (legacy
// CDNA3 shape) at ~17 cyc effective/instr with a 14-deep dependent chain;
// 16x16x32_f16 halves the instruction count and the 2-acc split cuts the
// dependency chain to 4.
__global__ __launch_bounds__(NTHR, 4) void snse_kernel(
    const float* __restrict__ g_xr, const float* __restrict__ g_xi,
    const float* __restrict__ g_ti, const float* __restrict__ g_c00,
    const float* __restrict__ g_wx, const float* __restrict__ g_wc,
    const _Float16* __restrict__ Wb,
    float* __restrict__ g_out)
{
    __shared__ uint SEe[NSER * SSTR];                       // 19520 B
    __shared__ uint SEo[NSER * SSTR];                       // 19520 B (shift-1)
    __shared__ _Float16 CB[NSLOT * CSTR];                   // 35088 B
    __shared__ _Float16 s_xr_h[2][XSTR], s_xi_h[2][XSTR];   //  3712 B

    const int tid = threadIdx.x;
    const int b   = blockIdx.y;
    const int l0  = blockIdx.x * TL;

    const float tdb    = g_ti[b * 4 + 0];
    const float P      = expf(tdb * 0.23025850929940457f) * 0.5f;
    const float sP     = sqrtf(P);
    const float inv_sP = 1.0f / sP;
    const float C00    = g_c00[0];

    // ---- stage x (f16, scaled) ----
    for (int idx = tid; idx < 2 * NPX; idx += NTHR) {
        int pidx = idx >> 1, ch = idx & 1;
        int m = l0 - 2 + pidx;
        int mw = m < 0 ? m + M_LEN : (m >= M_LEN ? m - M_LEN : m);
        int gg = (b * M_LEN + mw) * 2 + ch;
        s_xr_h[ch][pidx] = (_Float16)(g_xr[gg] * sP);
        s_xi_h[ch][pidx] = (_Float16)(g_xi[gg] * sP);
    }
    __syncthreads();

    // ---- stage series (packed f16 pairs), zero beyond NPS ----
    for (int p = tid; p < SSTR; p += NTHR) {
        float v0[NSER], v1[NSER];
#pragma unroll
        for (int a = 0; a < NSER; ++a) { v0[a] = 0.f; v1[a] = 0.f; }
        const int m0 = 2 * p, m1 = 2 * p + 1;
        if (m0 < NPS) calc_series(s_xr_h, s_xi_h, m0, v0);
        if (m1 < NPS) calc_series(s_xr_h, s_xi_h, m1, v1);
#pragma unroll
        for (int a = 0; a < NSER; ++a) {
            _Float16 h0 = (_Float16)v0[a], h1 = (_Float16)v1[a];
            ushort_ s0, s1; __builtin_memcpy(&s0, &h0, 2); __builtin_memcpy(&s1, &h1, 2);
            SEe[a * SSTR + p] = (uint)s0 | ((uint)s1 << 16);
        }
    }
    __syncthreads();

    // ---- shifted copy: SEo[d] = elements (2d+1, 2d+2) ----
    for (int d = tid; d < NSER * SSTR; d += NTHR) {
        int row = d / SSTR, cc = d - row * SSTR;
        uint lo = SEe[d] >> 16;
        uint hi = (cc < SSTR - 1) ? (SEe[d + 1] << 16) : 0u;
        SEo[d] = lo | hi;
    }
    __syncthreads();

    // ---- MFMA conv phase ----
    // wave w: rho = parity, hs = position half, sgrp = series group (10 each)
    // chunks c=0..3: 16 stride-2 positions starting pbase0+32c
    // A[m][k] = S[pbase0 + 32c + 2m + k]; lane: m=cn, k = 32kt + 8gq + j
    {
        const int w    = tid >> 6;
        const int lane = tid & 63;
        const int cn   = lane & 15;   // A row m / B-C col
        const int gq   = lane >> 4;   // k-group / C row-quad
        const int rho  = w & 1, hs = (w >> 1) & 1, sgrp = w >> 2;
        const int pbase0 = hs * 128 + rho;

        h8 Bf[KT];
#pragma unroll
        for (int i = 0; i < KT; ++i) {
            h8 t; __builtin_memcpy(&t, Wb + cn * 224 + 32 * i + 8 * gq, 16);
            Bf[i] = t;
        }

        const uint* SEp = rho ? SEo : SEe;
        // dword base for k-tile T: dw0 + 16*T, read 4 consecutive dwords
        const int dw0 = ((pbase0 - rho) >> 1) + cn + 4 * gq;

#pragma unroll 1
        for (int as = 0; as < 10; ++as) {
            const int a = sgrp * 10 + as;
            const uint* Pa = SEp + a * SSTR + dw0;

            h8 F[KT];
#pragma unroll
            for (int i = 0; i < KT; ++i)
                F[i] = mk8(Pa[16 * i], Pa[16 * i + 1], Pa[16 * i + 2], Pa[16 * i + 3]);

            // slot for this lane's column (or -1)
            int slot = -1;
            if (a < 4) {
                if (cn == (a >> 1)) slot = a;
            } else {
                int cb = 2 + 4 * ((a - 4) >> 3);
                int ci = cn - cb;
                if (ci >= 0 && ci < 4) slot = 4 + (a - 4) * 4 + ci;
            }

#pragma unroll
            for (int c = 0; c < 4; ++c) {
                // split accumulators: halves the dependent-MFMA chain
                f4 Cc0 = {0.f, 0.f, 0.f, 0.f};
                f4 Cc1 = {0.f, 0.f, 0.f, 0.f};
#pragma unroll
                for (int kt = 0; kt < KT; ++kt) {
                    const int fi = (c + kt) % KT;
                    if (kt & 1)
                        Cc1 = __builtin_amdgcn_mfma_f32_16x16x32_f16(
                            F[fi], Bf[kt], Cc1, 0, 0, 0);
                    else
                        Cc0 = __builtin_amdgcn_mfma_f32_16x16x32_f16(
                            F[fi], Bf[kt], Cc0, 0, 0, 0);
                }
                if (c < 3) {   // prefetch next chunk's 1 new k-tile (c+7)
                    const int t = KT + c;
                    F[c % KT] = mk8(Pa[16 * t], Pa[16 * t + 1],
                                    Pa[16 * t + 2], Pa[16 * t + 3]);
                }
                if (slot >= 0) {
                    const int pb = pbase0 + 32 * c;
#pragma unroll
                    for (int r = 0; r < 4; ++r)
                        CB[slot * CSTR + pb + 2 * (4 * gq + r)] =
                            (_Float16)(Cc0[r] + Cc1[r]);
                }
            }
        }
    }
    __syncthreads();

    // ---- epilogue: one (pos, nn) unit per thread ----
    {
        const int pos = tid >> 1, nn = tid & 1;
        const int l = l0 + pos;

        const float wx100 = (float)(_Float16)g_wx[T_HALF];
        const float wc100 = (float)(_Float16)g_wc[T_HALF];

        float acc_ix = (float)CB[nn * CSTR + pos];
        float acc_qr = (float)CB[2 * CSTR + pos];
        float acc_qi = (float)CB[3 * CSTR + pos];

        const int pc = pos + T_HALF;
        acc_ix = fmaf(-wx100, half_of(SEe[nn * SSTR + (pc >> 1)], pc & 1), acc_ix);
        acc_qr = fmaf(-wc100, half_of(SEe[2 * SSTR + (pc >> 1)], pc & 1), acc_qr);
        acc_qi = fmaf(-wc100, half_of(SEe[3 * SSTR + (pc >> 1)], pc & 1), acc_qi);

        float fAr[4], fAi[4], fBr[4], fBi[4];
#pragma unroll
        for (int sg = 0; sg < 2; ++sg) {
            const int sip = 2 + sg, sin_ = 1 - sg;
            const int sb = 4 + 32 * sg;
            // S(si,ci) = CB[(sb + 4*si + ci)][pos]
#define SRD(si, ci) ((float)CB[(sb + 4 * (si) + (ci)) * CSTR + pos])
            fAr[sip]  = SRD(nn, 0)     - SRD(2 + nn, 1);
            fAi[sip]  = SRD(nn, 1)     + SRD(2 + nn, 0);
            fAr[sin_] = SRD(nn, 2)     + SRD(2 + nn, 3);
            fAi[sin_] = SRD(nn, 3)     - SRD(2 + nn, 2);
            fBr[sip]  = SRD(4 + nn, 0) - SRD(6 + nn, 1);
            fBi[sip]  = SRD(4 + nn, 1) + SRD(6 + nn, 0);
            fBr[sin_] = SRD(5 - nn, 2) + SRD(7 - nn, 3);
            fBi[sin_] = SRD(5 - nn, 3) - SRD(7 - nn, 2);
#undef SRD
        }

        const int xc = pos + T_HALF + 2;
        float X0r = (float)s_xr_h[0][xc], X0i = (float)s_xi_h[0][xc];
        float X1r = (float)s_xr_h[1][xc], X1i = (float)s_xi_h[1][xc];
        float pw  = X0r * X0r + X0i * X0i + X1r * X1r + X1i * X1i;
        float phi = C00 * pw + 2.f * acc_ix;
        float sph, cph;
        __sincosf(phi, &sph, &cph);
        float qcr = acc_qr;
        float qci = nn ? -acc_qi : acc_qi;
        float br_ = nn ? X1r : X0r, bi_ = nn ? X1i : X0i;
        float or_ = nn ? X0r : X1r, oi_ = nn ? X0i : X1i;
        float ici_r = -(or_ * qci + oi_ * qcr);
        float ici_i =   or_ * qcr - oi_ * qci;
        float fw_r = 0.f, fw_i = 0.f;
        const int ssf[4] = {-2, -1, 1, 2};
#pragma unroll
        for (int si = 0; si < 4; ++si) {
            int sx = xc - ssf[si];
            float xnr  = (float)s_xr_h[nn][sx],     xni = (float)s_xi_h[nn][sx];
            float xor_ = (float)s_xr_h[1 - nn][sx], xoi = (float)s_xi_h[1 - nn][sx];
            fw_r += xnr * fAr[si] - xni * fAi[si]
                  + xor_ * fBr[si] - xoi * fBi[si];
            fw_i += xnr * fAi[si] + xni * fAr[si]
                  + xor_ * fBi[si] + xoi * fBr[si];
        }
        float out_r = br_ * cph - bi_ * sph + ici_r + fw_r;
        float out_i = br_ * sph + bi_ * cph + ici_i + fw_i;
        if (l < L_OUT) {
            int oidx = (((b * L_OUT) + l) * 2 + nn) * 2;
            g_out[oidx]     = out_r * inv_sP;
            g_out[oidx + 1] = out_i * inv_sP;
        }
    }
}

extern "C" void kernel_launch(void* const* d_in, const int* in_sizes, int n_in,
                              void* d_out, int out_size, void* d_ws, size_t ws_size,
                              hipStream_t stream) {
    const float* xr  = (const float*)d_in[0];
    const float* xi  = (const float*)d_in[1];
    const float* ti  = (const float*)d_in[2];
    const float* c00 = (const float*)d_in[3];
    const float* wx  = (const float*)d_in[4];
    const float* wc  = (const float*)d_in[5];
    const float* wr  = (const float*)d_in[6];
    const float* wi  = (const float*)d_in[7];
    float* out = (float*)d_out;
    _Float16* Wb = (_Float16*)d_ws;   // 16*224*2 = 7168 bytes

    prep_weights<<<dim3((16 * 224 + 255) / 256), dim3(256), 0, stream>>>(wx, wc, wr, wi, Wb);

    dim3 grid(NTILES, B_SZ, 1);
    dim3 block(NTHR, 1, 1);
    snse_kernel<<<grid, block, 0, stream>>>(xr, xi, ti, c00, wx, wc, Wb, out);
}

// Round 10
// 168.744 us; speedup vs baseline: 1.3915x; 1.0119x over previous
//
#include <hip/hip_runtime.h>
#include <math.h>

#define M_LEN 40000
#define B_SZ 16
#define K_TAPS 201
#define T_HALF 100
#define L_OUT 39800
#define TL 256               // outputs per block
#define NTILES 156           // ceil(L_OUT / TL)
#define NP 456               // TL + K_TAPS - 1
#define NPS 458              // NP + 2 (guard)
#define NPX 460              // x positions staged
#define XSTR 464             // x f16 stride
#define SSTR 244             // series row stride in dwords (488 f16 elems)
#define NSER 20
#define KT 7                 // k-tiles: 7*32 = 224 >= 201 taps (rest zero-wt)
#define CSTR 258             // Cbuf position stride (f16)
#define NSLOT 68
#define NTHR 512

typedef unsigned int uint;
typedef unsigned short ushort_;
typedef __fp16 h8 __attribute__((ext_vector_type(8)));
typedef float f4 __attribute__((ext_vector_type(4)));

static __device__ __forceinline__ float half_of(uint u, int hi) {
    ushort_ us = hi ? (ushort_)(u >> 16) : (ushort_)(u & 0xffffu);
    _Float16 h; __builtin_memcpy(&h, &us, 2); return (float)h;
}
static __device__ __forceinline__ h8 mk8(uint a, uint b, uint c, uint d) {
    uint uu[4] = {a, b, c, d}; h8 h; __builtin_memcpy(&h, uu, 16); return h;
}

// ---------------- prep kernel: B weight panel [16 cols][224 taps] f16 --------
// col 0: wx; col 1: wc; cols 2+4sg+{0,1,2,3}: wPr,wPi,wNr,wNi for sg; 10-15: 0
__global__ void prep_weights(const float* __restrict__ wx, const float* __restrict__ wc,
                             const float* __restrict__ wr, const float* __restrict__ wi,
                             _Float16* __restrict__ Wb) {
    int idx = blockIdx.x * 256 + threadIdx.x;
    if (idx >= 16 * 224) return;
    int n = idx / 224, t = idx % 224;
    float f = 0.f;
    if (n == 0)      f = (t <= 200) ? wx[t] : 0.f;
    else if (n == 1) f = (t <= 200) ? wc[t] : 0.f;
    else if (n < 10) {
        int q = n - 2, sg = q >> 2, c = q & 3;
        if (c < 2) {                       // wPr / wPi
            f = (t <= 200) ? ((c == 1) ? wi : wr)[(2 + sg) * K_TAPS + t] : 0.f;
        } else {                           // wNr / wNi (shifted taps)
            int tt = t - (sg + 1);
            f = (tt >= 0 && tt <= 200) ? ((c == 3) ? wi : wr)[(1 - sg) * K_TAPS + tt] : 0.f;
        }
    }
    Wb[idx] = (_Float16)f;
}

// ---------------- series construction (identical math to verified R0-R6) -----
static __device__ __forceinline__ void calc_series(
        const _Float16 (*sxr)[XSTR], const _Float16 (*sxi)[XSTR], int pos, float* v) {
    const int ix = pos + 2;
    float x0r = (float)sxr[0][ix], x0i = (float)sxi[0][ix];
    float x1r = (float)sxr[1][ix], x1i = (float)sxi[1][ix];
    float p0 = x0r * x0r + x0i * x0i;
    float p1 = x1r * x1r + x1i * x1i;
    v[0] = 2.f * p0 + p1;
    v[1] = 2.f * p1 + p0;
    v[2] = x0r * x1r + x0i * x1i;       // qr
    v[3] = x0i * x1r - x0r * x1i;       // qi
#pragma unroll
    for (int sg = 0; sg < 2; ++sg) {
        const int jx = ix - (sg + 1);
        float a0r = (float)sxr[0][jx], a0i = (float)sxi[0][jx];
        float a1r = (float)sxr[1][jx], a1i = (float)sxi[1][jx];
        float U0r = x0r * a0r + x0i * a0i;
        float U0i = x0i * a0r - x0r * a0i;
        float U1r = x1r * a1r + x1i * a1i;
        float U1i = x1i * a1r - x1r * a1i;
        const int ba = 4 + sg * 8;
        v[ba + 0] = 2.f * U0r + U1r;        // A0r
        v[ba + 1] = 2.f * U1r + U0r;        // A1r
        v[ba + 2] = 2.f * U0i + U1i;        // A0i
        v[ba + 3] = 2.f * U1i + U0i;        // A1i
        v[ba + 4] = x0r * a1r + x0i * a1i;  // Br0
        v[ba + 5] = x1r * a0r + x1i * a0i;  // Br1
        v[ba + 6] = x0i * a1r - x0r * a1i;  // Bi0
        v[ba + 7] = x1i * a0r - x1r * a0i;  // Bi1
    }
}

// Verified R6 MFMA conv kernel + series-loop unroll 2 (latency fix: at 4
// waves/SIMD the 52 dependent ds_read_b32/series (~120cy) and 2-chain MFMA
// cannot be hidden; interleaving two independent series streams doubles ILP
// with zero arithmetic change -> bitwise-identical output).
__global__ __launch_bounds__(NTHR, 4) void snse_kernel(
    const float* __restrict__ g_xr, const float* __restrict__ g_xi,
    const float* __restrict__ g_ti, const float* __restrict__ g_c00,
    const float* __restrict__ g_wx, const float* __restrict__ g_wc,
    const _Float16* __restrict__ Wb,
    float* __restrict__ g_out)
{
    __shared__ uint SEe[NSER * SSTR];                       // 19520 B
    __shared__ uint SEo[NSER * SSTR];                       // 19520 B (shift-1)
    __shared__ _Float16 CB[NSLOT * CSTR];                   // 35088 B
    __shared__ _Float16 s_xr_h[2][XSTR], s_xi_h[2][XSTR];   //  3712 B

    const int tid = threadIdx.x;
    const int b   = blockIdx.y;
    const int l0  = blockIdx.x * TL;

    const float tdb    = g_ti[b * 4 + 0];
    const float P      = expf(tdb * 0.23025850929940457f) * 0.5f;
    const float sP     = sqrtf(P);
    const float inv_sP = 1.0f / sP;
    const float C00    = g_c00[0];

    // ---- stage x (f16, scaled) ----
    for (int idx = tid; idx < 2 * NPX; idx += NTHR) {
        int pidx = idx >> 1, ch = idx & 1;
        int m = l0 - 2 + pidx;
        int mw = m < 0 ? m + M_LEN : (m >= M_LEN ? m - M_LEN : m);
        int gg = (b * M_LEN + mw) * 2 + ch;
        s_xr_h[ch][pidx] = (_Float16)(g_xr[gg] * sP);
        s_xi_h[ch][pidx] = (_Float16)(g_xi[gg] * sP);
    }
    __syncthreads();

    // ---- stage series (packed f16 pairs), zero beyond NPS ----
    for (int p = tid; p < SSTR; p += NTHR) {
        float v0[NSER], v1[NSER];
#pragma unroll
        for (int a = 0; a < NSER; ++a) { v0[a] = 0.f; v1[a] = 0.f; }
        const int m0 = 2 * p, m1 = 2 * p + 1;
        if (m0 < NPS) calc_series(s_xr_h, s_xi_h, m0, v0);
        if (m1 < NPS) calc_series(s_xr_h, s_xi_h, m1, v1);
#pragma unroll
        for (int a = 0; a < NSER; ++a) {
            _Float16 h0 = (_Float16)v0[a], h1 = (_Float16)v1[a];
            ushort_ s0, s1; __builtin_memcpy(&s0, &h0, 2); __builtin_memcpy(&s1, &h1, 2);
            SEe[a * SSTR + p] = (uint)s0 | ((uint)s1 << 16);
        }
    }
    __syncthreads();

    // ---- shifted copy: SEo[d] = elements (2d+1, 2d+2) ----
    for (int d = tid; d < NSER * SSTR; d += NTHR) {
        int row = d / SSTR, cc = d - row * SSTR;
        uint lo = SEe[d] >> 16;
        uint hi = (cc < SSTR - 1) ? (SEe[d + 1] << 16) : 0u;
        SEo[d] = lo | hi;
    }
    __syncthreads();

    // ---- MFMA conv phase ----
    // wave w: rho = parity, hs = position half, sgrp = series group (10 each)
    // chunks c=0..3: 16 stride-2 positions starting pbase0+32c
    // A[m][k] = S[pbase0 + 32c + 2m + k]; lane: m=cn, k = 32kt + 8gq + j
    {
        const int w    = tid >> 6;
        const int lane = tid & 63;
        const int cn   = lane & 15;   // A row m / B-C col
        const int gq   = lane >> 4;   // k-group / C row-quad
        const int rho  = w & 1, hs = (w >> 1) & 1, sgrp = w >> 2;
        const int pbase0 = hs * 128 + rho;

        h8 Bf[KT];
#pragma unroll
        for (int i = 0; i < KT; ++i) {
            h8 t; __builtin_memcpy(&t, Wb + cn * 224 + 32 * i + 8 * gq, 16);
            Bf[i] = t;
        }

        const uint* SEp = rho ? SEo : SEe;
        // dword base for k-tile T: dw0 + 16*T, read 4 consecutive dwords
        const int dw0 = ((pbase0 - rho) >> 1) + cn + 4 * gq;

#pragma unroll 2
        for (int as = 0; as < 10; ++as) {
            const int a = sgrp * 10 + as;
            const uint* Pa = SEp + a * SSTR + dw0;

            h8 F[KT];
#pragma unroll
            for (int i = 0; i < KT; ++i)
                F[i] = mk8(Pa[16 * i], Pa[16 * i + 1], Pa[16 * i + 2], Pa[16 * i + 3]);

            // slot for this lane's column (or -1)
            int slot = -1;
            if (a < 4) {
                if (cn == (a >> 1)) slot = a;
            } else {
                int cb = 2 + 4 * ((a - 4) >> 3);
                int ci = cn - cb;
                if (ci >= 0 && ci < 4) slot = 4 + (a - 4) * 4 + ci;
            }

#pragma unroll
            for (int c = 0; c < 4; ++c) {
                // split accumulators: halves the dependent-MFMA chain
                f4 Cc0 = {0.f, 0.f, 0.f, 0.f};
                f4 Cc1 = {0.f, 0.f, 0.f, 0.f};
#pragma unroll
                for (int kt = 0; kt < KT; ++kt) {
                    const int fi = (c + kt) % KT;
                    if (kt & 1)
                        Cc1 = __builtin_amdgcn_mfma_f32_16x16x32_f16(
                            F[fi], Bf[kt], Cc1, 0, 0, 0);
                    else
                        Cc0 = __builtin_amdgcn_mfma_f32_16x16x32_f16(
                            F[fi], Bf[kt], Cc0, 0, 0, 0);
                }
                if (c < 3) {   // prefetch next chunk's 1 new k-tile (c+7)
                    const int t = KT + c;
                    F[c % KT] = mk8(Pa[16 * t], Pa[16 * t + 1],
                                    Pa[16 * t + 2], Pa[16 * t + 3]);
                }
                if (slot >= 0) {
                    const int pb = pbase0 + 32 * c;
#pragma unroll
                    for (int r = 0; r < 4; ++r)
                        CB[slot * CSTR + pb + 2 * (4 * gq + r)] =
                            (_Float16)(Cc0[r] + Cc1[r]);
                }
            }
        }
    }
    __syncthreads();

    // ---- epilogue: one (pos, nn) unit per thread ----
    {
        const int pos = tid >> 1, nn = tid & 1;
        const int l = l0 + pos;

        const float wx100 = (float)(_Float16)g_wx[T_HALF];
        const float wc100 = (float)(_Float16)g_wc[T_HALF];

        float acc_ix = (float)CB[nn * CSTR + pos];
        float acc_qr = (float)CB[2 * CSTR + pos];
        float acc_qi = (float)CB[3 * CSTR + pos];

        const int pc = pos + T_HALF;
        acc_ix = fmaf(-wx100, half_of(SEe[nn * SSTR + (pc >> 1)], pc & 1), acc_ix);
        acc_qr = fmaf(-wc100, half_of(SEe[2 * SSTR + (pc >> 1)], pc & 1), acc_qr);
        acc_qi = fmaf(-wc100, half_of(SEe[3 * SSTR + (pc >> 1)], pc & 1), acc_qi);

        float fAr[4], fAi[4], fBr[4], fBi[4];
#pragma unroll
        for (int sg = 0; sg < 2; ++sg) {
            const int sip = 2 + sg, sin_ = 1 - sg;
            const int sb = 4 + 32 * sg;
            // S(si,ci) = CB[(sb + 4*si + ci)][pos]
#define SRD(si, ci) ((float)CB[(sb + 4 * (si) + (ci)) * CSTR + pos])
            fAr[sip]  = SRD(nn, 0)     - SRD(2 + nn, 1);
            fAi[sip]  = SRD(nn, 1)     + SRD(2 + nn, 0);
            fAr[sin_] = SRD(nn, 2)     + SRD(2 + nn, 3);
            fAi[sin_] = SRD(nn, 3)     - SRD(2 + nn, 2);
            fBr[sip]  = SRD(4 + nn, 0) - SRD(6 + nn, 1);
            fBi[sip]  = SRD(4 + nn, 1) + SRD(6 + nn, 0);
            fBr[sin_] = SRD(5 - nn, 2) + SRD(7 - nn, 3);
            fBi[sin_] = SRD(5 - nn, 3) - SRD(7 - nn, 2);
#undef SRD
        }

        const int xc = pos + T_HALF + 2;
        float X0r = (float)s_xr_h[0][xc], X0i = (float)s_xi_h[0][xc];
        float X1r = (float)s_xr_h[1][xc], X1i = (float)s_xi_h[1][xc];
        float pw  = X0r * X0r + X0i * X0i + X1r * X1r + X1i * X1i;
        float phi = C00 * pw + 2.f * acc_ix;
        float sph, cph;
        __sincosf(phi, &sph, &cph);
        float qcr = acc_qr;
        float qci = nn ? -acc_qi : acc_qi;
        float br_ = nn ? X1r : X0r, bi_ = nn ? X1i : X0i;
        float or_ = nn ? X0r : X1r, oi_ = nn ? X0i : X1i;
        float ici_r = -(or_ * qci + oi_ * qcr);
        float ici_i =   or_ * qcr - oi_ * qci;
        float fw_r = 0.f, fw_i = 0.f;
        const int ssf[4] = {-2, -1, 1, 2};
#pragma unroll
        for (int si = 0; si < 4; ++si) {
            int sx = xc - ssf[si];
            float xnr  = (float)s_xr_h[nn][sx],     xni = (float)s_xi_h[nn][sx];
            float xor_ = (float)s_xr_h[1 - nn][sx], xoi = (float)s_xi_h[1 - nn][sx];
            fw_r += xnr * fAr[si] - xni * fAi[si]
                  + xor_ * fBr[si] - xoi * fBi[si];
            fw_i += xnr * fAi[si] + xni * fAr[si]
                  + xor_ * fBi[si] + xoi * fBr[si];
        }
        float out_r = br_ * cph - bi_ * sph + ici_r + fw_r;
        float out_i = br_ * sph + bi_ * cph + ici_i + fw_i;
        if (l < L_OUT) {
            int oidx = (((b * L_OUT) + l) * 2 + nn) * 2;
            g_out[oidx]     = out_r * inv_sP;
            g_out[oidx + 1] = out_i * inv_sP;
        }
    }
}

extern "C" void kernel_launch(void* const* d_in, const int* in_sizes, int n_in,
                              void* d_out, int out_size, void* d_ws, size_t ws_size,
                              hipStream_t stream) {
    const float* xr  = (const float*)d_in[0];
    const float* xi  = (const float*)d_in[1];
    const float* ti  = (const float*)d_in[2];
    const float* c00 = (const float*)d_in[3];
    const float* wx  = (const float*)d_in[4];
    const float* wc  = (const float*)d_in[5];
    const float* wr  = (const float*)d_in[6];
    const float* wi  = (const float*)d_in[7];
    float* out = (float*)d_out;
    _Float16* Wb = (_Float16*)d_ws;   // 16*224*2 = 7168 bytes

    prep_weights<<<dim3((16 * 224 + 255) / 256), dim3(256), 0, stream>>>(wx, wc, wr, wi, Wb);

    dim3 grid(NTILES, B_SZ, 1);
    dim3 block(NTHR, 1, 1);
    snse_kernel<<<grid, block, 0, stream>>>(xr, xi, ti, c00, wx, wc, Wb, out);
}

// Round 11
// 167.981 us; speedup vs baseline: 1.3978x; 1.0045x over previous
//
#include <hip/hip_runtime.h>
#include <math.h>

#define M_LEN 40000
#define B_SZ 16
#define K_TAPS 201
#define T_HALF 100
#define L_OUT 39800
#define TL 256               // outputs per block
#define NTILES 156           // ceil(L_OUT / TL)
#define NP 456               // TL + K_TAPS - 1
#define NPS 458              // NP + 2 (guard)
#define NPX 460              // x positions staged
#define XSTR 464             // x f16 stride
#define SSTR 244             // series row stride in dwords (488 f16 elems)
#define NSER 20
#define KT 7                 // k-tiles: 7*32 = 224 >= 201 taps (rest zero-wt)
#define NSLOT 68
#define NTHR 512

typedef unsigned int uint;
typedef unsigned short ushort_;
typedef __fp16 h2 __attribute__((ext_vector_type(2)));
typedef __fp16 h8 __attribute__((ext_vector_type(8)));
typedef float f4 __attribute__((ext_vector_type(4)));

static __device__ __forceinline__ float half_of(uint u, int hi) {
    ushort_ us = hi ? (ushort_)(u >> 16) : (ushort_)(u & 0xffffu);
    _Float16 h; __builtin_memcpy(&h, &us, 2); return (float)h;
}
static __device__ __forceinline__ uint pk2(float a, float b) {
    h2 h = __builtin_amdgcn_cvt_pkrtz(a, b);
    uint r; __builtin_memcpy(&r, &h, 4); return r;
}
static __device__ __forceinline__ h8 mk8(uint a, uint b, uint c, uint d) {
    uint uu[4] = {a, b, c, d}; h8 h; __builtin_memcpy(&h, uu, 16); return h;
}

// ---------------- prep kernel: B weight panel [16 cols][224 taps] f16 --------
// col 0: wx; col 1: wc; cols 2+4sg+{0,1,2,3}: wPr,wPi,wNr,wNi for sg; 10-15: 0
__global__ void prep_weights(const float* __restrict__ wx, const float* __restrict__ wc,
                             const float* __restrict__ wr, const float* __restrict__ wi,
                             _Float16* __restrict__ Wb) {
    int idx = blockIdx.x * 256 + threadIdx.x;
    if (idx >= 16 * 224) return;
    int n = idx / 224, t = idx % 224;
    float f = 0.f;
    if (n == 0)      f = (t <= 200) ? wx[t] : 0.f;
    else if (n == 1) f = (t <= 200) ? wc[t] : 0.f;
    else if (n < 10) {
        int q = n - 2, sg = q >> 2, c = q & 3;
        if (c < 2) {                       // wPr / wPi
            f = (t <= 200) ? ((c == 1) ? wi : wr)[(2 + sg) * K_TAPS + t] : 0.f;
        } else {                           // wNr / wNi (shifted taps)
            int tt = t - (sg + 1);
            f = (tt >= 0 && tt <= 200) ? ((c == 3) ? wi : wr)[(1 - sg) * K_TAPS + tt] : 0.f;
        }
    }
    Wb[idx] = (_Float16)f;
}

// ---------------- series construction (identical math to verified R0-R10) ----
static __device__ __forceinline__ void calc_series(
        const _Float16 (*sxr)[XSTR], const _Float16 (*sxi)[XSTR], int pos, float* v) {
    const int ix = pos + 2;
    float x0r = (float)sxr[0][ix], x0i = (float)sxi[0][ix];
    float x1r = (float)sxr[1][ix], x1i = (float)sxi[1][ix];
    float p0 = x0r * x0r + x0i * x0i;
    float p1 = x1r * x1r + x1i * x1i;
    v[0] = 2.f * p0 + p1;
    v[1] = 2.f * p1 + p0;
    v[2] = x0r * x1r + x0i * x1i;       // qr
    v[3] = x0i * x1r - x0r * x1i;       // qi
#pragma unroll
    for (int sg = 0; sg < 2; ++sg) {
        const int jx = ix - (sg + 1);
        float a0r = (float)sxr[0][jx], a0i = (float)sxi[0][jx];
        float a1r = (float)sxr[1][jx], a1i = (float)sxi[1][jx];
        float U0r = x0r * a0r + x0i * a0i;
        float U0i = x0i * a0r - x0r * a0i;
        float U1r = x1r * a1r + x1i * a1i;
        float U1i = x1i * a1r - x1r * a1i;
        const int ba = 4 + sg * 8;
        v[ba + 0] = 2.f * U0r + U1r;        // A0r
        v[ba + 1] = 2.f * U1r + U0r;        // A1r
        v[ba + 2] = 2.f * U0i + U1i;        // A0i
        v[ba + 3] = 2.f * U1i + U0i;        // A1i
        v[ba + 4] = x0r * a1r + x0i * a1i;  // Br0
        v[ba + 5] = x1r * a0r + x1i * a0i;  // Br1
        v[ba + 6] = x0i * a1r - x0r * a1i;  // Bi0
        v[ba + 7] = x1i * a0r - x1r * a0i;  // Bi1
    }
}

// R10 structure + two issue-count fixes:
// (1) kt-outer MFMA loop: all 10 F fragments up-front, 4 independent chunk
//     accumulators -> dependency distance 4 (no chain stall), one lgkm wait.
// (2) CB parity-plane layout [slot][par][pos>>1]: lane's 4 C-rows are
//     contiguous f16 -> 2 cvt_pkrtz + 1 ds_write_b64 per chunk instead of
//     4 scalar f16 stores + 8 VALU (saves ~360 instr/thread).
__global__ __launch_bounds__(NTHR, 4) void snse_kernel(
    const float* __restrict__ g_xr, const float* __restrict__ g_xi,
    const float* __restrict__ g_ti, const float* __restrict__ g_c00,
    const float* __restrict__ g_wx, const float* __restrict__ g_wc,
    const _Float16* __restrict__ Wb,
    float* __restrict__ g_out)
{
    __shared__ uint SEe[NSER * SSTR];                       // 19520 B
    __shared__ uint SEo[NSER * SSTR];                       // 19520 B (shift-1)
    __shared__ __align__(16) uint CB2[NSLOT * 128];         // 34816 B
    __shared__ _Float16 s_xr_h[2][XSTR], s_xi_h[2][XSTR];   //  3712 B

    const int tid = threadIdx.x;
    const int b   = blockIdx.y;
    const int l0  = blockIdx.x * TL;

    const float tdb    = g_ti[b * 4 + 0];
    const float P      = expf(tdb * 0.23025850929940457f) * 0.5f;
    const float sP     = sqrtf(P);
    const float inv_sP = 1.0f / sP;
    const float C00    = g_c00[0];

    // ---- stage x (f16, scaled) ----
    for (int idx = tid; idx < 2 * NPX; idx += NTHR) {
        int pidx = idx >> 1, ch = idx & 1;
        int m = l0 - 2 + pidx;
        int mw = m < 0 ? m + M_LEN : (m >= M_LEN ? m - M_LEN : m);
        int gg = (b * M_LEN + mw) * 2 + ch;
        s_xr_h[ch][pidx] = (_Float16)(g_xr[gg] * sP);
        s_xi_h[ch][pidx] = (_Float16)(g_xi[gg] * sP);
    }
    __syncthreads();

    // ---- stage series (packed f16 pairs), zero beyond NPS ----
    for (int p = tid; p < SSTR; p += NTHR) {
        float v0[NSER], v1[NSER];
#pragma unroll
        for (int a = 0; a < NSER; ++a) { v0[a] = 0.f; v1[a] = 0.f; }
        const int m0 = 2 * p, m1 = 2 * p + 1;
        if (m0 < NPS) calc_series(s_xr_h, s_xi_h, m0, v0);
        if (m1 < NPS) calc_series(s_xr_h, s_xi_h, m1, v1);
#pragma unroll
        for (int a = 0; a < NSER; ++a) {
            _Float16 h0 = (_Float16)v0[a], h1 = (_Float16)v1[a];
            ushort_ s0, s1; __builtin_memcpy(&s0, &h0, 2); __builtin_memcpy(&s1, &h1, 2);
            SEe[a * SSTR + p] = (uint)s0 | ((uint)s1 << 16);
        }
    }
    __syncthreads();

    // ---- shifted copy: SEo[d] = elements (2d+1, 2d+2) ----
    for (int d = tid; d < NSER * SSTR; d += NTHR) {
        int row = d / SSTR, cc = d - row * SSTR;
        uint lo = SEe[d] >> 16;
        uint hi = (cc < SSTR - 1) ? (SEe[d + 1] << 16) : 0u;
        SEo[d] = lo | hi;
    }
    __syncthreads();

    // ---- MFMA conv phase ----
    // wave w: rho = parity, hs = position half, sgrp = series group (10 each)
    // chunks c=0..3: 16 stride-2 positions starting pbase0+32c
    // A[m][k] = S[pbase0 + 32c + 2m + k]; lane: m=cn, k = 32kt + 8gq + j
    // chunk c, k-tile kt uses fragment c+kt (fragment j = 32j-elem offset)
    {
        const int w    = tid >> 6;
        const int lane = tid & 63;
        const int cn   = lane & 15;   // A row m / B-C col
        const int gq   = lane >> 4;   // k-group / C row-quad
        const int rho  = w & 1, hs = (w >> 1) & 1, sgrp = w >> 2;

        h8 Bf[KT];
#pragma unroll
        for (int i = 0; i < KT; ++i) {
            h8 t; __builtin_memcpy(&t, Wb + cn * 224 + 32 * i + 8 * gq, 16);
            Bf[i] = t;
        }

        const uint* SEp = rho ? SEo : SEe;
        const int pbase0 = hs * 128 + rho;
        const int dw0 = ((pbase0 - rho) >> 1) + cn + 4 * gq;
        // CB2 uint index base: slot*128 + rho*64 + 32*hs + 8*c + 2*gq
        const int ub0 = rho * 64 + 32 * hs + 2 * gq;

#pragma unroll 1
        for (int as = 0; as < 10; ++as) {
            const int a = sgrp * 10 + as;
            const uint* Pa = SEp + a * SSTR + dw0;

            h8 F[10];
#pragma unroll
            for (int i = 0; i < 10; ++i)
                F[i] = mk8(Pa[16 * i], Pa[16 * i + 1], Pa[16 * i + 2], Pa[16 * i + 3]);

            // slot for this lane's column (or -1)
            int slot = -1;
            if (a < 4) {
                if (cn == (a >> 1)) slot = a;
            } else {
                int cb = 2 + 4 * ((a - 4) >> 3);
                int ci = cn - cb;
                if (ci >= 0 && ci < 4) slot = 4 + (a - 4) * 4 + ci;
            }

            f4 Cc[4] = {};
#pragma unroll
            for (int kt = 0; kt < KT; ++kt) {
#pragma unroll
                for (int c = 0; c < 4; ++c)
                    Cc[c] = __builtin_amdgcn_mfma_f32_16x16x32_f16(
                        F[c + kt], Bf[kt], Cc[c], 0, 0, 0);
            }

            if (slot >= 0) {
                const int ub = slot * 128 + ub0;
#pragma unroll
                for (int c = 0; c < 4; ++c) {
                    uint2 v;
                    v.x = pk2(Cc[c][0], Cc[c][1]);
                    v.y = pk2(Cc[c][2], Cc[c][3]);
                    *(uint2*)&CB2[ub + 8 * c] = v;
                }
            }
        }
    }
    __syncthreads();

    // ---- epilogue: one (pos, nn) unit per thread ----
    {
        const int pos = tid >> 1, nn = tid & 1;
        const int l = l0 + pos;

        const float wx100 = (float)(_Float16)g_wx[T_HALF];
        const float wc100 = (float)(_Float16)g_wc[T_HALF];

        // CB2 addressing: parity plane + half-position
        const int par = pos & 1, hp = pos >> 1;
        const int cbb = par * 64 + (hp >> 1);
        const int hl  = hp & 1;

        float acc_ix = half_of(CB2[nn * 128 + cbb], hl);
        float acc_qr = half_of(CB2[2 * 128 + cbb], hl);
        float acc_qi = half_of(CB2[3 * 128 + cbb], hl);

        const int pc = pos + T_HALF;
        acc_ix = fmaf(-wx100, half_of(SEe[nn * SSTR + (pc >> 1)], pc & 1), acc_ix);
        acc_qr = fmaf(-wc100, half_of(SEe[2 * SSTR + (pc >> 1)], pc & 1), acc_qr);
        acc_qi = fmaf(-wc100, half_of(SEe[3 * SSTR + (pc >> 1)], pc & 1), acc_qi);

        float fAr[4], fAi[4], fBr[4], fBi[4];
#pragma unroll
        for (int sg = 0; sg < 2; ++sg) {
            const int sip = 2 + sg, sin_ = 1 - sg;
            const int sb = 4 + 32 * sg;
#define SRD(si, ci) half_of(CB2[(sb + 4 * (si) + (ci)) * 128 + cbb], hl)
            fAr[sip]  = SRD(nn, 0)     - SRD(2 + nn, 1);
            fAi[sip]  = SRD(nn, 1)     + SRD(2 + nn, 0);
            fAr[sin_] = SRD(nn, 2)     + SRD(2 + nn, 3);
            fAi[sin_] = SRD(nn, 3)     - SRD(2 + nn, 2);
            fBr[sip]  = SRD(4 + nn, 0) - SRD(6 + nn, 1);
            fBi[sip]  = SRD(4 + nn, 1) + SRD(6 + nn, 0);
            fBr[sin_] = SRD(5 - nn, 2) + SRD(7 - nn, 3);
            fBi[sin_] = SRD(5 - nn, 3) - SRD(7 - nn, 2);
#undef SRD
        }

        const int xc = pos + T_HALF + 2;
        float X0r = (float)s_xr_h[0][xc], X0i = (float)s_xi_h[0][xc];
        float X1r = (float)s_xr_h[1][xc], X1i = (float)s_xi_h[1][xc];
        float pw  = X0r * X0r + X0i * X0i + X1r * X1r + X1i * X1i;
        float phi = C00 * pw + 2.f * acc_ix;
        float sph, cph;
        __sincosf(phi, &sph, &cph);
        float qcr = acc_qr;
        float qci = nn ? -acc_qi : acc_qi;
        float br_ = nn ? X1r : X0r, bi_ = nn ? X1i : X0i;
        float or_ = nn ? X0r : X1r, oi_ = nn ? X0i : X1i;
        float ici_r = -(or_ * qci + oi_ * qcr);
        float ici_i =   or_ * qcr - oi_ * qci;
        float fw_r = 0.f, fw_i = 0.f;
        const int ssf[4] = {-2, -1, 1, 2};
#pragma unroll
        for (int si = 0; si < 4; ++si) {
            int sx = xc - ssf[si];
            float xnr  = (float)s_xr_h[nn][sx],     xni = (float)s_xi_h[nn][sx];
            float xor_ = (float)s_xr_h[1 - nn][sx], xoi = (float)s_xi_h[1 - nn][sx];
            fw_r += xnr * fAr[si] - xni * fAi[si]
                  + xor_ * fBr[si] - xoi * fBi[si];
            fw_i += xnr * fAi[si] + xni * fAr[si]
                  + xor_ * fBi[si] + xoi * fBr[si];
        }
        float out_r = br_ * cph - bi_ * sph + ici_r + fw_r;
        float out_i = br_ * sph + bi_ * cph + ici_i + fw_i;
        if (l < L_OUT) {
            int oidx = (((b * L_OUT) + l) * 2 + nn) * 2;
            g_out[oidx]     = out_r * inv_sP;
            g_out[oidx + 1] = out_i * inv_sP;
        }
    }
}

extern "C" void kernel_launch(void* const* d_in, const int* in_sizes, int n_in,
                              void* d_out, int out_size, void* d_ws, size_t ws_size,
                              hipStream_t stream) {
    const float* xr  = (const float*)d_in[0];
    const float* xi  = (const float*)d_in[1];
    const float* ti  = (const float*)d_in[2];
    const float* c00 = (const float*)d_in[3];
    const float* wx  = (const float*)d_in[4];
    const float* wc  = (const float*)d_in[5];
    const float* wr  = (const float*)d_in[6];
    const float* wi  = (const float*)d_in[7];
    float* out = (float*)d_out;
    _Float16* Wb = (_Float16*)d_ws;   // 16*224*2 = 7168 bytes

    prep_weights<<<dim3((16 * 224 + 255) / 256), dim3(256), 0, stream>>>(wx, wc, wr, wi, Wb);

    dim3 grid(NTILES, B_SZ, 1);
    dim3 block(NTHR, 1, 1);
    snse_kernel<<<grid, block, 0, stream>>>(xr, xi, ti, c00, wx, wc, Wb, out);
}

// Round 12
// 165.432 us; speedup vs baseline: 1.4193x; 1.0154x over previous
//
#include <hip/hip_runtime.h>
#include <math.h>

#define M_LEN 40000
#define B_SZ 16
#define K_TAPS 201
#define T_HALF 100
#define L_OUT 39800
#define TL 256               // outputs per block
#define NTILES 156           // ceil(L_OUT / TL)
#define NP 456               // TL + K_TAPS - 1
#define NPS 458              // NP + 2 (guard)
#define NPX 460              // x positions staged
#define XSTR 464             // x f16 stride
#define SSTR 244             // series row stride in dwords (488 f16 elems)
#define NSER 20
#define KT 7                 // k-tiles: 7*32 = 224 >= 201 taps (rest zero-wt)
#define CBS 136              // CB2 slot stride in dwords; 136 % 32 = 8 -> the 16
                             // writing lanes hit banks {8ci+2gq} (16 distinct):
                             // zero write conflicts. 128 was = 0 mod 32 -> 4-way
                             // conflict on EVERY CB2 write (11.85M cyc, R11).
#define NSLOT 68
#define NTHR 512

typedef unsigned int uint;
typedef unsigned short ushort_;
typedef __fp16 h2 __attribute__((ext_vector_type(2)));
typedef __fp16 h8 __attribute__((ext_vector_type(8)));
typedef float f4 __attribute__((ext_vector_type(4)));

static __device__ __forceinline__ float half_of(uint u, int hi) {
    ushort_ us = hi ? (ushort_)(u >> 16) : (ushort_)(u & 0xffffu);
    _Float16 h; __builtin_memcpy(&h, &us, 2); return (float)h;
}
static __device__ __forceinline__ uint pk2(float a, float b) {
    h2 h = __builtin_amdgcn_cvt_pkrtz(a, b);
    uint r; __builtin_memcpy(&r, &h, 4); return r;
}
static __device__ __forceinline__ h8 mk8(uint a, uint b, uint c, uint d) {
    uint uu[4] = {a, b, c, d}; h8 h; __builtin_memcpy(&h, uu, 16); return h;
}

// ---------------- prep kernel: B weight panel [16 cols][224 taps] f16 --------
// col 0: wx; col 1: wc; cols 2+4sg+{0,1,2,3}: wPr,wPi,wNr,wNi for sg; 10-15: 0
__global__ void prep_weights(const float* __restrict__ wx, const float* __restrict__ wc,
                             const float* __restrict__ wr, const float* __restrict__ wi,
                             _Float16* __restrict__ Wb) {
    int idx = blockIdx.x * 256 + threadIdx.x;
    if (idx >= 16 * 224) return;
    int n = idx / 224, t = idx % 224;
    float f = 0.f;
    if (n == 0)      f = (t <= 200) ? wx[t] : 0.f;
    else if (n == 1) f = (t <= 200) ? wc[t] : 0.f;
    else if (n < 10) {
        int q = n - 2, sg = q >> 2, c = q & 3;
        if (c < 2) {                       // wPr / wPi
            f = (t <= 200) ? ((c == 1) ? wi : wr)[(2 + sg) * K_TAPS + t] : 0.f;
        } else {                           // wNr / wNi (shifted taps)
            int tt = t - (sg + 1);
            f = (tt >= 0 && tt <= 200) ? ((c == 3) ? wi : wr)[(1 - sg) * K_TAPS + tt] : 0.f;
        }
    }
    Wb[idx] = (_Float16)f;
}

// ---------------- series construction (identical math to verified R0-R11) ----
static __device__ __forceinline__ void calc_series(
        const _Float16 (*sxr)[XSTR], const _Float16 (*sxi)[XSTR], int pos, float* v) {
    const int ix = pos + 2;
    float x0r = (float)sxr[0][ix], x0i = (float)sxi[0][ix];
    float x1r = (float)sxr[1][ix], x1i = (float)sxi[1][ix];
    float p0 = x0r * x0r + x0i * x0i;
    float p1 = x1r * x1r + x1i * x1i;
    v[0] = 2.f * p0 + p1;
    v[1] = 2.f * p1 + p0;
    v[2] = x0r * x1r + x0i * x1i;       // qr
    v[3] = x0i * x1r - x0r * x1i;       // qi
#pragma unroll
    for (int sg = 0; sg < 2; ++sg) {
        const int jx = ix - (sg + 1);
        float a0r = (float)sxr[0][jx], a0i = (float)sxi[0][jx];
        float a1r = (float)sxr[1][jx], a1i = (float)sxi[1][jx];
        float U0r = x0r * a0r + x0i * a0i;
        float U0i = x0i * a0r - x0r * a0i;
        float U1r = x1r * a1r + x1i * a1i;
        float U1i = x1i * a1r - x1r * a1i;
        const int ba = 4 + sg * 8;
        v[ba + 0] = 2.f * U0r + U1r;        // A0r
        v[ba + 1] = 2.f * U1r + U0r;        // A1r
        v[ba + 2] = 2.f * U0i + U1i;        // A0i
        v[ba + 3] = 2.f * U1i + U0i;        // A1i
        v[ba + 4] = x0r * a1r + x0i * a1i;  // Br0
        v[ba + 5] = x1r * a0r + x1i * a0i;  // Br1
        v[ba + 6] = x0i * a1r - x0r * a1i;  // Bi0
        v[ba + 7] = x1i * a0r - x1r * a0i;  // Bi1
    }
}

// R11 structure (kt-outer MFMA, parity-plane CB) + CB2 stride 128 -> 136 to
// kill the write-side bank conflicts R11 introduced. Single-variable change.
__global__ __launch_bounds__(NTHR, 4) void snse_kernel(
    const float* __restrict__ g_xr, const float* __restrict__ g_xi,
    const float* __restrict__ g_ti, const float* __restrict__ g_c00,
    const float* __restrict__ g_wx, const float* __restrict__ g_wc,
    const _Float16* __restrict__ Wb,
    float* __restrict__ g_out)
{
    __shared__ uint SEe[NSER * SSTR];                       // 19520 B
    __shared__ uint SEo[NSER * SSTR];                       // 19520 B (shift-1)
    __shared__ __align__(16) uint CB2[NSLOT * CBS];         // 36992 B
    __shared__ _Float16 s_xr_h[2][XSTR], s_xi_h[2][XSTR];   //  3712 B

    const int tid = threadIdx.x;
    const int b   = blockIdx.y;
    const int l0  = blockIdx.x * TL;

    const float tdb    = g_ti[b * 4 + 0];
    const float P      = expf(tdb * 0.23025850929940457f) * 0.5f;
    const float sP     = sqrtf(P);
    const float inv_sP = 1.0f / sP;
    const float C00    = g_c00[0];

    // ---- stage x (f16, scaled) ----
    for (int idx = tid; idx < 2 * NPX; idx += NTHR) {
        int pidx = idx >> 1, ch = idx & 1;
        int m = l0 - 2 + pidx;
        int mw = m < 0 ? m + M_LEN : (m >= M_LEN ? m - M_LEN : m);
        int gg = (b * M_LEN + mw) * 2 + ch;
        s_xr_h[ch][pidx] = (_Float16)(g_xr[gg] * sP);
        s_xi_h[ch][pidx] = (_Float16)(g_xi[gg] * sP);
    }
    __syncthreads();

    // ---- stage series (packed f16 pairs), zero beyond NPS ----
    for (int p = tid; p < SSTR; p += NTHR) {
        float v0[NSER], v1[NSER];
#pragma unroll
        for (int a = 0; a < NSER; ++a) { v0[a] = 0.f; v1[a] = 0.f; }
        const int m0 = 2 * p, m1 = 2 * p + 1;
        if (m0 < NPS) calc_series(s_xr_h, s_xi_h, m0, v0);
        if (m1 < NPS) calc_series(s_xr_h, s_xi_h, m1, v1);
#pragma unroll
        for (int a = 0; a < NSER; ++a) {
            _Float16 h0 = (_Float16)v0[a], h1 = (_Float16)v1[a];
            ushort_ s0, s1; __builtin_memcpy(&s0, &h0, 2); __builtin_memcpy(&s1, &h1, 2);
            SEe[a * SSTR + p] = (uint)s0 | ((uint)s1 << 16);
        }
    }
    __syncthreads();

    // ---- shifted copy: SEo[d] = elements (2d+1, 2d+2) ----
    for (int d = tid; d < NSER * SSTR; d += NTHR) {
        int row = d / SSTR, cc = d - row * SSTR;
        uint lo = SEe[d] >> 16;
        uint hi = (cc < SSTR - 1) ? (SEe[d + 1] << 16) : 0u;
        SEo[d] = lo | hi;
    }
    __syncthreads();

    // ---- MFMA conv phase ----
    // wave w: rho = parity, hs = position half, sgrp = series group (10 each)
    // chunks c=0..3: 16 stride-2 positions starting pbase0+32c
    // A[m][k] = S[pbase0 + 32c + 2m + k]; lane: m=cn, k = 32kt + 8gq + j
    // chunk c, k-tile kt uses fragment c+kt (fragment j = 32j-elem offset)
    {
        const int w    = tid >> 6;
        const int lane = tid & 63;
        const int cn   = lane & 15;   // A row m / B-C col
        const int gq   = lane >> 4;   // k-group / C row-quad
        const int rho  = w & 1, hs = (w >> 1) & 1, sgrp = w >> 2;

        h8 Bf[KT];
#pragma unroll
        for (int i = 0; i < KT; ++i) {
            h8 t; __builtin_memcpy(&t, Wb + cn * 224 + 32 * i + 8 * gq, 16);
            Bf[i] = t;
        }

        const uint* SEp = rho ? SEo : SEe;
        const int pbase0 = hs * 128 + rho;
        const int dw0 = ((pbase0 - rho) >> 1) + cn + 4 * gq;
        // CB2 uint index base: slot*CBS + rho*64 + 32*hs + 8*c + 2*gq
        const int ub0 = rho * 64 + 32 * hs + 2 * gq;

#pragma unroll 1
        for (int as = 0; as < 10; ++as) {
            const int a = sgrp * 10 + as;
            const uint* Pa = SEp + a * SSTR + dw0;

            h8 F[10];
#pragma unroll
            for (int i = 0; i < 10; ++i)
                F[i] = mk8(Pa[16 * i], Pa[16 * i + 1], Pa[16 * i + 2], Pa[16 * i + 3]);

            // slot for this lane's column (or -1)
            int slot = -1;
            if (a < 4) {
                if (cn == (a >> 1)) slot = a;
            } else {
                int cb = 2 + 4 * ((a - 4) >> 3);
                int ci = cn - cb;
                if (ci >= 0 && ci < 4) slot = 4 + (a - 4) * 4 + ci;
            }

            f4 Cc[4] = {};
#pragma unroll
            for (int kt = 0; kt < KT; ++kt) {
#pragma unroll
                for (int c = 0; c < 4; ++c)
                    Cc[c] = __builtin_amdgcn_mfma_f32_16x16x32_f16(
                        F[c + kt], Bf[kt], Cc[c], 0, 0, 0);
            }

            if (slot >= 0) {
                const int ub = slot * CBS + ub0;
#pragma unroll
                for (int c = 0; c < 4; ++c) {
                    uint2 v;
                    v.x = pk2(Cc[c][0], Cc[c][1]);
                    v.y = pk2(Cc[c][2], Cc[c][3]);
                    *(uint2*)&CB2[ub + 8 * c] = v;
                }
            }
        }
    }
    __syncthreads();

    // ---- epilogue: one (pos, nn) unit per thread ----
    {
        const int pos = tid >> 1, nn = tid & 1;
        const int l = l0 + pos;

        const float wx100 = (float)(_Float16)g_wx[T_HALF];
        const float wc100 = (float)(_Float16)g_wc[T_HALF];

        // CB2 addressing: parity plane + half-position
        const int par = pos & 1, hp = pos >> 1;
        const int cbb = par * 64 + (hp >> 1);
        const int hl  = hp & 1;

        float acc_ix = half_of(CB2[nn * CBS + cbb], hl);
        float acc_qr = half_of(CB2[2 * CBS + cbb], hl);
        float acc_qi = half_of(CB2[3 * CBS + cbb], hl);

        const int pc = pos + T_HALF;
        acc_ix = fmaf(-wx100, half_of(SEe[nn * SSTR + (pc >> 1)], pc & 1), acc_ix);
        acc_qr = fmaf(-wc100, half_of(SEe[2 * SSTR + (pc >> 1)], pc & 1), acc_qr);
        acc_qi = fmaf(-wc100, half_of(SEe[3 * SSTR + (pc >> 1)], pc & 1), acc_qi);

        float fAr[4], fAi[4], fBr[4], fBi[4];
#pragma unroll
        for (int sg = 0; sg < 2; ++sg) {
            const int sip = 2 + sg, sin_ = 1 - sg;
            const int sb = 4 + 32 * sg;
#define SRD(si, ci) half_of(CB2[(sb + 4 * (si) + (ci)) * CBS + cbb], hl)
            fAr[sip]  = SRD(nn, 0)     - SRD(2 + nn, 1);
            fAi[sip]  = SRD(nn, 1)     + SRD(2 + nn, 0);
            fAr[sin_] = SRD(nn, 2)     + SRD(2 + nn, 3);
            fAi[sin_] = SRD(nn, 3)     - SRD(2 + nn, 2);
            fBr[sip]  = SRD(4 + nn, 0) - SRD(6 + nn, 1);
            fBi[sip]  = SRD(4 + nn, 1) + SRD(6 + nn, 0);
            fBr[sin_] = SRD(5 - nn, 2) + SRD(7 - nn, 3);
            fBi[sin_] = SRD(5 - nn, 3) - SRD(7 - nn, 2);
#undef SRD
        }

        const int xc = pos + T_HALF + 2;
        float X0r = (float)s_xr_h[0][xc], X0i = (float)s_xi_h[0][xc];
        float X1r = (float)s_xr_h[1][xc], X1i = (float)s_xi_h[1][xc];
        float pw  = X0r * X0r + X0i * X0i + X1r * X1r + X1i * X1i;
        float phi = C00 * pw + 2.f * acc_ix;
        float sph, cph;
        __sincosf(phi, &sph, &cph);
        float qcr = acc_qr;
        float qci = nn ? -acc_qi : acc_qi;
        float br_ = nn ? X1r : X0r, bi_ = nn ? X1i : X0i;
        float or_ = nn ? X0r : X1r, oi_ = nn ? X0i : X1i;
        float ici_r = -(or_ * qci + oi_ * qcr);
        float ici_i =   or_ * qcr - oi_ * qci;
        float fw_r = 0.f, fw_i = 0.f;
        const int ssf[4] = {-2, -1, 1, 2};
#pragma unroll
        for (int si = 0; si < 4; ++si) {
            int sx = xc - ssf[si];
            float xnr  = (float)s_xr_h[nn][sx],     xni = (float)s_xi_h[nn][sx];
            float xor_ = (float)s_xr_h[1 - nn][sx], xoi = (float)s_xi_h[1 - nn][sx];
            fw_r += xnr * fAr[si] - xni * fAi[si]
                  + xor_ * fBr[si] - xoi * fBi[si];
            fw_i += xnr * fAi[si] + xni * fAr[si]
                  + xor_ * fBi[si] + xoi * fBr[si];
        }
        float out_r = br_ * cph - bi_ * sph + ici_r + fw_r;
        float out_i = br_ * sph + bi_ * cph + ici_i + fw_i;
        if (l < L_OUT) {
            int oidx = (((b * L_OUT) + l) * 2 + nn) * 2;
            g_out[oidx]     = out_r * inv_sP;
            g_out[oidx + 1] = out_i * inv_sP;
        }
    }
}

extern "C" void kernel_launch(void* const* d_in, const int* in_sizes, int n_in,
                              void* d_out, int out_size, void* d_ws, size_t ws_size,
                              hipStream_t stream) {
    const float* xr  = (const float*)d_in[0];
    const float* xi  = (const float*)d_in[1];
    const float* ti  = (const float*)d_in[2];
    const float* c00 = (const float*)d_in[3];
    const float* wx  = (const float*)d_in[4];
    const float* wc  = (const float*)d_in[5];
    const float* wr  = (const float*)d_in[6];
    const float* wi  = (const float*)d_in[7];
    float* out = (float*)d_out;
    _Float16* Wb = (_Float16*)d_ws;   // 16*224*2 = 7168 bytes

    prep_weights<<<dim3((16 * 224 + 255) / 256), dim3(256), 0, stream>>>(wx, wc, wr, wi, Wb);

    dim3 grid(NTILES, B_SZ, 1);
    dim3 block(NTHR, 1, 1);
    snse_kernel<<<grid, block, 0, stream>>>(xr, xi, ti, c00, wx, wc, Wb, out);
}